// Round 6
// baseline (2174.797 us; speedup 1.0000x reference)
//
#include <hip/hip_runtime.h>
#include <math.h>

// ---------------------------------------------------------------------------
// CapsNet forward on MI355X.
// R6: conv2 = R5 structure (B frags direct global->reg w/ 1-step prefetch,
//     A from parity-split LDS slab) but 16-way K-split -> grid 1024 =
//     4 blocks/CU = 4 waves/SIMD (R5 was grid-limited at 2: MfmaUtil 40%,
//     all pipes <45%, occupancy 21% -> latency-bound). Per-XCD weight set
//     ~2.75 MB now fits 4 MB L2.
// ---------------------------------------------------------------------------

typedef float floatx4 __attribute__((ext_vector_type(4)));
typedef __bf16 bf16x8 __attribute__((ext_vector_type(8)));

#define XHI_OFF 0u
#define XLO_OFF 52428800u
#define WHI_OFF 104857600u          // 84*32*256*8 shorts = 11010048 B
#define WLO_OFF 115867648u
#define Y2_OFF  126877696u
#define VP_OFF  136314880u
#define Y2_BYTES 9437184u

__device__ __forceinline__ void bf16split(float v, short& hs, short& ls) {
  unsigned u = __builtin_bit_cast(unsigned, v);
  unsigned r = (u + 0x7FFFu + ((u >> 16) & 1u)) & 0xFFFF0000u;
  hs = (short)(r >> 16);
  float lo = v - __builtin_bit_cast(float, r);
  unsigned u2 = __builtin_bit_cast(unsigned, lo);
  unsigned r2 = u2 + 0x7FFFu + ((u2 >> 16) & 1u);
  ls = (short)(r2 >> 16);
}

// ============================ conv1: 9x9 s1 + ReLU ==========================
// Emits x_hi/x_lo bf16 in [b][pos(400)][ic(256)] layout (GEMM-A friendly).
__global__ __launch_bounds__(320) void conv1_k(
    const float* __restrict__ inp, const float* __restrict__ W1,
    const float* __restrict__ b1, short* __restrict__ xhi,
    short* __restrict__ xlo) {
  __shared__ __align__(16) float img[784];
  __shared__ float wl[81 * 34];
  const int blk = blockIdx.x;
  const int b = blk >> 3;
  const int cbase = (blk & 7) * 32;
  const int t = threadIdx.x;

  const float4* src = (const float4*)(inp + b * 784);
  for (int idx = t; idx < 196; idx += 320) ((float4*)img)[idx] = src[idx];
  for (int idx = t; idx < 2592; idx += 320) {
    int c = idx / 81, tap = idx - c * 81;
    wl[tap * 34 + c] = W1[(cbase + c) * 81 + tap];
  }
  __syncthreads();

  const int oy = t >> 4;
  const int ct = t & 15;
  const int c0 = cbase + ct * 2;
  const float bias0 = b1[c0], bias1 = b1[c0 + 1];
  float acc0[20], acc1[20];
#pragma unroll
  for (int ox = 0; ox < 20; ox++) { acc0[ox] = bias0; acc1[ox] = bias1; }

#pragma unroll 1
  for (int i = 0; i < 9; i++) {
    float wr0[9], wr1[9];
#pragma unroll
    for (int j = 0; j < 9; j++) {
      float2 wv = *(const float2*)&wl[(i * 9 + j) * 34 + ct * 2];
      wr0[j] = wv.x; wr1[j] = wv.y;
    }
    float xr[28];
    const float4* rp = (const float4*)&img[(oy + i) * 28];
#pragma unroll
    for (int k = 0; k < 7; k++) {
      float4 v = rp[k];
      xr[4 * k] = v.x; xr[4 * k + 1] = v.y; xr[4 * k + 2] = v.z; xr[4 * k + 3] = v.w;
    }
#pragma unroll
    for (int j = 0; j < 9; j++)
#pragma unroll
      for (int ox = 0; ox < 20; ox++) {
        acc0[ox] = fmaf(xr[ox + j], wr0[j], acc0[ox]);
        acc1[ox] = fmaf(xr[ox + j], wr1[j], acc1[ox]);
      }
  }
  const long pbase = (long)(b * 400 + oy * 20) * 256 + c0;
#pragma unroll
  for (int ox = 0; ox < 20; ox++) {
    float v0 = fmaxf(acc0[ox], 0.f), v1 = fmaxf(acc1[ox], 0.f);
    short h0, l0, h1, l1;
    bf16split(v0, h0, l0);
    bf16split(v1, h1, l1);
    long a = pbase + (long)ox * 256;
    *(short2*)&xhi[a] = make_short2(h0, h1);
    *(short2*)&xlo[a] = make_short2(l0, l1);
  }
}

// ======= W2 transform: fp32 [oc][ic][81] -> bf16 hi/lo, 84-tap padded =======
// out layout: [tap(84)][icg(32)][oc(256)][ics(8)]; taps 81..83 zero.
__global__ __launch_bounds__(256) void wtrans_k(
    const float* __restrict__ W2, short* __restrict__ whi,
    short* __restrict__ wlo) {
  const int idx = blockIdx.x * 256 + threadIdx.x;  // < 5505024
  const int ics = idx & 7;
  const int oc = (idx >> 3) & 255;
  const int icg = (idx >> 11) & 31;
  const int tap = idx >> 16;
  short h = 0, l = 0;
  if (tap < 81) {
    const int ic = icg * 8 + ics;
    bf16split(W2[(oc * 256 + ic) * 81 + tap], h, l);
  }
  whi[idx] = h;
  wlo[idx] = l;
}

// ================= conv2: MFMA bf16-split implicit GEMM =====================
// grid 1024: ks = blk&15 (2 icg each, XCD-L2-resident slice), mb = blk>>4.
// Block M144(9 m-tiles) x N256; 4 waves, each 9m x 4n (N64/wave).
// K-step 32 = 4 taps(quad) x 8 ic(elem). B frags: direct global->reg with
// 1-step prefetch; A frags from parity-split LDS slab. 84 taps (3 zero-pad).
__global__ __launch_bounds__(256, 4) void conv2_k(
    const short* __restrict__ xhi, const short* __restrict__ xlo,
    const short* __restrict__ whi, const short* __restrict__ wlo,
    float* __restrict__ y2) {
  // slab: [parity(2)][img(4)][iy(20)][ixh(10)][ic(8)] shorts = 12800 (25.6KB)
  __shared__ __align__(16) short slabA[12800];

  const int blk = blockIdx.x;
  const int ks = blk & 15;
  const int mb = blk >> 4;
  const int b0 = mb * 4;
  const int t = threadIdx.x;
  const int lane = t & 63;
  const int q = lane >> 4;
  const int ln16 = lane & 15;
  const int wv = t >> 6;

  int combo[9];
#pragma unroll
  for (int mt = 0; mt < 9; mt++) {
    int row = mt * 16 + ln16;
    int im = row / 36;
    int pos = row - im * 36;
    int oy = pos / 6, ox = pos - oy * 6;
    combo[mt] = im * 1600 + oy * 160 + ox * 8;
  }

  floatx4 acc[9][4];
#pragma unroll
  for (int mt = 0; mt < 9; mt++)
#pragma unroll
    for (int nt = 0; nt < 4; nt++) acc[mt][nt] = (floatx4)0.f;

#pragma unroll 1
  for (int icg = 0; icg < 2; icg++) {
    const int icgG = ks * 2 + icg;
    const long icoff = (long)icgG * 8;
    // per-lane weight base (shorts): ((tap*32 + icgG)*256 + oc)*8
    const long wb0 = ((long)icgG * 256 + wv * 64 + ln16) * 8 + (long)q * 65536;

    // ---------------- HI phase: A_hi * (B_hi + B_lo) ----------------
    __syncthreads();
    for (int idx = t; idx < 1600; idx += 256) {
      int im = idx / 400, p = idx - im * 400;
      int iy = p / 20, ix = p - iy * 20;
      int dst = (ix & 1) * 6400 + im * 1600 + iy * 80 + (ix >> 1) * 8;
      *(uint4*)&slabA[dst] =
          *(const uint4*)&xhi[((long)(b0 + im) * 400 + p) * 256 + icoff];
    }
    __syncthreads();

    {
      bf16x8 cbh[4], cbl[4];
#pragma unroll
      for (int nt = 0; nt < 4; nt++) {
        long a = wb0 + nt * 128;              // t0 = 0
        cbh[nt] = *(const bf16x8*)&whi[a];
        cbl[nt] = *(const bf16x8*)&wlo[a];
      }
#pragma unroll 1
      for (int kst = 0; kst < 21; kst++) {
        // prefetch next k-step's B frags (clamped; taps 80..83 are zero-pad)
        const int t0n = (kst < 20) ? (kst + 1) * 4 : 80;
        bf16x8 nbh[4], nbl[4];
#pragma unroll
        for (int nt = 0; nt < 4; nt++) {
          long a = wb0 + (long)t0n * 65536 + nt * 128;  // 1 tap = 65536 shorts
          nbh[nt] = *(const bf16x8*)&whi[a];
          nbl[nt] = *(const bf16x8*)&wlo[a];
        }
        const int tap = kst * 4 + q;
        const int i = tap / 9, j = tap - i * 9;
        const int aoff = (j & 1) * 6400 + i * 80 + (j >> 1) * 8;
#pragma unroll
        for (int mt = 0; mt < 9; mt++) {
          bf16x8 a = *(const bf16x8*)&slabA[aoff + combo[mt]];
#pragma unroll
          for (int nt = 0; nt < 4; nt++) {
            acc[mt][nt] = __builtin_amdgcn_mfma_f32_16x16x32_bf16(a, cbh[nt], acc[mt][nt], 0, 0, 0);
            acc[mt][nt] = __builtin_amdgcn_mfma_f32_16x16x32_bf16(a, cbl[nt], acc[mt][nt], 0, 0, 0);
          }
        }
#pragma unroll
        for (int nt = 0; nt < 4; nt++) { cbh[nt] = nbh[nt]; cbl[nt] = nbl[nt]; }
      }
    }

    // ---------------- LO phase: A_lo * B_hi ----------------
    __syncthreads();
    for (int idx = t; idx < 1600; idx += 256) {
      int im = idx / 400, p = idx - im * 400;
      int iy = p / 20, ix = p - iy * 20;
      int dst = (ix & 1) * 6400 + im * 1600 + iy * 80 + (ix >> 1) * 8;
      *(uint4*)&slabA[dst] =
          *(const uint4*)&xlo[((long)(b0 + im) * 400 + p) * 256 + icoff];
    }
    __syncthreads();

    {
      bf16x8 cbh[4];
#pragma unroll
      for (int nt = 0; nt < 4; nt++) cbh[nt] = *(const bf16x8*)&whi[wb0 + nt * 128];
#pragma unroll 1
      for (int kst = 0; kst < 21; kst++) {
        const int t0n = (kst < 20) ? (kst + 1) * 4 : 80;
        bf16x8 nbh[4];
#pragma unroll
        for (int nt = 0; nt < 4; nt++)
          nbh[nt] = *(const bf16x8*)&whi[wb0 + (long)t0n * 65536 + nt * 128];
        const int tap = kst * 4 + q;
        const int i = tap / 9, j = tap - i * 9;
        const int aoff = (j & 1) * 6400 + i * 80 + (j >> 1) * 8;
#pragma unroll
        for (int mt = 0; mt < 9; mt++) {
          bf16x8 a = *(const bf16x8*)&slabA[aoff + combo[mt]];
#pragma unroll
          for (int nt = 0; nt < 4; nt++)
            acc[mt][nt] = __builtin_amdgcn_mfma_f32_16x16x32_bf16(a, cbh[nt], acc[mt][nt], 0, 0, 0);
        }
#pragma unroll
        for (int nt = 0; nt < 4; nt++) cbh[nt] = nbh[nt];
      }
    }
  }

  // epilogue: C/D layout col(n)=lane&15, row(m)=q*4+r; atomic over 16 ic-splits
#pragma unroll
  for (int mt = 0; mt < 9; mt++)
#pragma unroll
    for (int nt = 0; nt < 4; nt++) {
      int oc = wv * 64 + nt * 16 + ln16;
      int rowb = mb * 144 + mt * 16 + q * 4;
#pragma unroll
      for (int r = 0; r < 4; r++)
        atomicAdd(&y2[(long)(rowb + r) * 256 + oc], acc[mt][nt][r]);
    }
}

// ================= primary caps squash + predictions + routing ==============
// grid 8192 = g*256 + b; block 256.  y2 layout: [b][pos(36)][c(256)], pre-bias.
__global__ __launch_bounds__(256) void caps_k(
    const float* __restrict__ y2, const float* __restrict__ b2,
    const float* __restrict__ Wcaps, const float* __restrict__ b_route,
    float* __restrict__ vpart) {
  __shared__ float u[288];
  __shared__ float usc[36];
  __shared__ float up[5760];
  __shared__ float bl[360];
  __shared__ float cl[360];
  __shared__ float sv[160];
  __shared__ float vv[160];
  __shared__ float scale[10];
  const int blk = blockIdx.x;
  const int g = blk >> 8, b = blk & 255;
  const int t = threadIdx.x;

  for (int idx = t; idx < 288; idx += 256) {
    int s = idx >> 3, d = idx & 7;
    u[idx] = y2[((long)b * 36 + s) * 256 + g * 8 + d] + b2[g * 8 + d];
  }
  for (int idx = t; idx < 360; idx += 256) bl[idx] = b_route[g * 360 + idx];
  __syncthreads();
  if (t < 36) {
    float l2 = 0.f;
#pragma unroll
    for (int d = 0; d < 8; d++) { float v = u[t * 8 + d]; l2 = fmaf(v, v, l2); }
    float l = sqrtf(l2);
    usc[t] = (l2 / (1.f + l2)) / (l + 1e-8f);
  }
  __syncthreads();
  for (int idx = t; idx < 288; idx += 256) u[idx] *= usc[idx >> 3];
  __syncthreads();
  for (int idx = t; idx < 5760; idx += 256) {
    int s = idx / 160, k = idx - s * 160;
    const float* wp = Wcaps + (g * 36 + s) * 8 * 160 + k;
    float a = 0.f;
#pragma unroll
    for (int d = 0; d < 8; d++) a = fmaf(u[s * 8 + d], wp[d * 160], a);
    up[idx] = a;
  }
  __syncthreads();

  for (int r = 0; r < 3; r++) {
    if (t < 36) {
      float m = bl[t * 10];
#pragma unroll
      for (int oc = 1; oc < 10; oc++) m = fmaxf(m, bl[t * 10 + oc]);
      float e[10]; float sum = 0.f;
#pragma unroll
      for (int oc = 0; oc < 10; oc++) { e[oc] = expf(bl[t * 10 + oc] - m); sum += e[oc]; }
      float inv = 1.f / sum;
#pragma unroll
      for (int oc = 0; oc < 10; oc++) cl[t * 10 + oc] = e[oc] * inv;
    }
    __syncthreads();
    if (t < 160) {
      const int oc = t >> 4;
      float a = 0.f;
#pragma unroll 1
      for (int s = 0; s < 36; s++) a = fmaf(cl[s * 10 + oc], up[s * 160 + t], a);
      sv[t] = a;
    }
    __syncthreads();
    if (t < 10) {
      float l2 = 0.f;
#pragma unroll
      for (int od = 0; od < 16; od++) { float v = sv[t * 16 + od]; l2 = fmaf(v, v, l2); }
      scale[t] = (l2 / (1.f + l2)) / (sqrtf(l2) + 1e-8f);
    }
    __syncthreads();
    if (t < 160) vv[t] = sv[t] * scale[t >> 4];
    __syncthreads();
    if (r < 2) {
      for (int idx = t; idx < 360; idx += 256) {
        int s = idx / 10, oc = idx - s * 10;
        float a = 0.f;
#pragma unroll
        for (int od = 0; od < 16; od++)
          a = fmaf(up[s * 160 + oc * 16 + od], vv[oc * 16 + od], a);
        bl[idx] += a;
      }
      __syncthreads();
    }
  }
  if (t < 160) vpart[(b * 32 + g) * 160 + t] = vv[t];
}

// ================== final: sum over groups + probs ==========================
__global__ __launch_bounds__(192) void final_k(
    const float* __restrict__ vpart, float* __restrict__ out) {
  __shared__ float v[160];
  const int b = blockIdx.x, t = threadIdx.x;
  if (t < 160) {
    float a = 0.f;
#pragma unroll 1
    for (int g = 0; g < 32; g++) a += vpart[(b * 32 + g) * 160 + t];
    v[t] = a;
    out[b * 160 + t] = a;
  }
  __syncthreads();
  if (t < 10) {
    float l2 = 0.f;
#pragma unroll
    for (int od = 0; od < 16; od++) { float x = v[t * 16 + od]; l2 = fmaf(x, x, l2); }
    out[40960 + b * 10 + t] = sqrtf(l2);
  }
}

// ===========================================================================
extern "C" void kernel_launch(void* const* d_in, const int* in_sizes, int n_in,
                              void* d_out, int out_size, void* d_ws, size_t ws_size,
                              hipStream_t stream) {
  const float* inp     = (const float*)d_in[0];
  const float* W1      = (const float*)d_in[1];
  const float* b1      = (const float*)d_in[2];
  const float* W2      = (const float*)d_in[3];
  const float* b2      = (const float*)d_in[4];
  const float* Wcaps   = (const float*)d_in[5];
  const float* b_route = (const float*)d_in[6];
  float* out = (float*)d_out;
  char* ws = (char*)d_ws;

  short* xhi = (short*)(ws + XHI_OFF);
  short* xlo = (short*)(ws + XLO_OFF);
  short* whi = (short*)(ws + WHI_OFF);
  short* wlo = (short*)(ws + WLO_OFF);
  float* y2  = (float*)(ws + Y2_OFF);
  float* vp  = (float*)(ws + VP_OFF);

  hipMemsetAsync(y2, 0, Y2_BYTES, stream);
  conv1_k <<<2048, 320, 0, stream>>>(inp, W1, b1, xhi, xlo);
  wtrans_k<<<21504, 256, 0, stream>>>(W2, whi, wlo);
  conv2_k <<<1024, 256, 0, stream>>>(xhi, xlo, whi, wlo, y2);
  caps_k  <<<8192, 256, 0, stream>>>(y2, b2, Wcaps, b_route, vp);
  final_k <<<256, 192, 0, stream>>>(vp, out);
}

// Round 7
// 572.545 us; speedup vs baseline: 3.7985x; 3.7985x over previous
//
#include <hip/hip_runtime.h>
#include <math.h>

// ---------------------------------------------------------------------------
// CapsNet forward on MI355X.
// R7: revert to R5 launch config (grid 512, 2 blocks/CU -- occupancy is
//     structurally capped: 144 AGPR acc + ~112 VGPR = 256/thread; R6's
//     forced 4 waves/SIMD spilled acc to scratch, 9.2GB HBM). Restructured
//     conv2 inner loop for per-wave ILP: 3-mt batches, dependent-acc MFMA
//     distance 1 -> 12, B-lo loaded in-iteration (covered by hi block).
// ---------------------------------------------------------------------------

typedef float floatx4 __attribute__((ext_vector_type(4)));
typedef __bf16 bf16x8 __attribute__((ext_vector_type(8)));

#define XHI_OFF 0u
#define XLO_OFF 52428800u
#define WHI_OFF 104857600u          // 84*32*256*8 shorts = 11010048 B
#define WLO_OFF 115867648u
#define Y2_OFF  126877696u
#define VP_OFF  136314880u
#define Y2_BYTES 9437184u

__device__ __forceinline__ void bf16split(float v, short& hs, short& ls) {
  unsigned u = __builtin_bit_cast(unsigned, v);
  unsigned r = (u + 0x7FFFu + ((u >> 16) & 1u)) & 0xFFFF0000u;
  hs = (short)(r >> 16);
  float lo = v - __builtin_bit_cast(float, r);
  unsigned u2 = __builtin_bit_cast(unsigned, lo);
  unsigned r2 = u2 + 0x7FFFu + ((u2 >> 16) & 1u);
  ls = (short)(r2 >> 16);
}

// ============================ conv1: 9x9 s1 + ReLU ==========================
// Emits x_hi/x_lo bf16 in [b][pos(400)][ic(256)] layout (GEMM-A friendly).
__global__ __launch_bounds__(320) void conv1_k(
    const float* __restrict__ inp, const float* __restrict__ W1,
    const float* __restrict__ b1, short* __restrict__ xhi,
    short* __restrict__ xlo) {
  __shared__ __align__(16) float img[784];
  __shared__ float wl[81 * 34];
  const int blk = blockIdx.x;
  const int b = blk >> 3;
  const int cbase = (blk & 7) * 32;
  const int t = threadIdx.x;

  const float4* src = (const float4*)(inp + b * 784);
  for (int idx = t; idx < 196; idx += 320) ((float4*)img)[idx] = src[idx];
  for (int idx = t; idx < 2592; idx += 320) {
    int c = idx / 81, tap = idx - c * 81;
    wl[tap * 34 + c] = W1[(cbase + c) * 81 + tap];
  }
  __syncthreads();

  const int oy = t >> 4;
  const int ct = t & 15;
  const int c0 = cbase + ct * 2;
  const float bias0 = b1[c0], bias1 = b1[c0 + 1];
  float acc0[20], acc1[20];
#pragma unroll
  for (int ox = 0; ox < 20; ox++) { acc0[ox] = bias0; acc1[ox] = bias1; }

#pragma unroll 1
  for (int i = 0; i < 9; i++) {
    float wr0[9], wr1[9];
#pragma unroll
    for (int j = 0; j < 9; j++) {
      float2 wv = *(const float2*)&wl[(i * 9 + j) * 34 + ct * 2];
      wr0[j] = wv.x; wr1[j] = wv.y;
    }
    float xr[28];
    const float4* rp = (const float4*)&img[(oy + i) * 28];
#pragma unroll
    for (int k = 0; k < 7; k++) {
      float4 v = rp[k];
      xr[4 * k] = v.x; xr[4 * k + 1] = v.y; xr[4 * k + 2] = v.z; xr[4 * k + 3] = v.w;
    }
#pragma unroll
    for (int j = 0; j < 9; j++)
#pragma unroll
      for (int ox = 0; ox < 20; ox++) {
        acc0[ox] = fmaf(xr[ox + j], wr0[j], acc0[ox]);
        acc1[ox] = fmaf(xr[ox + j], wr1[j], acc1[ox]);
      }
  }
  const long pbase = (long)(b * 400 + oy * 20) * 256 + c0;
#pragma unroll
  for (int ox = 0; ox < 20; ox++) {
    float v0 = fmaxf(acc0[ox], 0.f), v1 = fmaxf(acc1[ox], 0.f);
    short h0, l0, h1, l1;
    bf16split(v0, h0, l0);
    bf16split(v1, h1, l1);
    long a = pbase + (long)ox * 256;
    *(short2*)&xhi[a] = make_short2(h0, h1);
    *(short2*)&xlo[a] = make_short2(l0, l1);
  }
}

// ======= W2 transform: fp32 [oc][ic][81] -> bf16 hi/lo, 84-tap padded =======
// out layout: [tap(84)][icg(32)][oc(256)][ics(8)]; taps 81..83 zero.
__global__ __launch_bounds__(256) void wtrans_k(
    const float* __restrict__ W2, short* __restrict__ whi,
    short* __restrict__ wlo) {
  const int idx = blockIdx.x * 256 + threadIdx.x;  // < 5505024
  const int ics = idx & 7;
  const int oc = (idx >> 3) & 255;
  const int icg = (idx >> 11) & 31;
  const int tap = idx >> 16;
  short h = 0, l = 0;
  if (tap < 81) {
    const int ic = icg * 8 + ics;
    bf16split(W2[(oc * 256 + ic) * 81 + tap], h, l);
  }
  whi[idx] = h;
  wlo[idx] = l;
}

// ================= conv2: MFMA bf16-split implicit GEMM =====================
// grid 512: ks = blk&7 (4 icg each, XCD-pinned L2 slice), mb = blk>>3.
// Block M144(9 m-tiles) x N256; 4 waves, each 9m x 4n (N64/wave).
// K-step 32 = 4 taps(quad) x 8 ic(elem). B-hi 1-step prefetch; B-lo loaded
// in-iteration (L2 latency covered by the 12+ MFMA hi block). A frags from
// parity-split LDS slab in 3-mt batches (dep-acc distance 12).
__global__ __launch_bounds__(256, 2) void conv2_k(
    const short* __restrict__ xhi, const short* __restrict__ xlo,
    const short* __restrict__ whi, const short* __restrict__ wlo,
    float* __restrict__ y2) {
  // slab: [parity(2)][img(4)][iy(20)][ixh(10)][ic(8)] shorts = 12800 (25.6KB)
  __shared__ __align__(16) short slabA[12800];

  const int blk = blockIdx.x;
  const int ks = blk & 7;
  const int mb = blk >> 3;
  const int b0 = mb * 4;
  const int t = threadIdx.x;
  const int lane = t & 63;
  const int q = lane >> 4;
  const int ln16 = lane & 15;
  const int wv = t >> 6;

  int combo[9];
#pragma unroll
  for (int mt = 0; mt < 9; mt++) {
    int row = mt * 16 + ln16;
    int im = row / 36;
    int pos = row - im * 36;
    int oy = pos / 6, ox = pos - oy * 6;
    combo[mt] = im * 1600 + oy * 160 + ox * 8;
  }

  floatx4 acc[9][4];
#pragma unroll
  for (int mt = 0; mt < 9; mt++)
#pragma unroll
    for (int nt = 0; nt < 4; nt++) acc[mt][nt] = (floatx4)0.f;

#pragma unroll 1
  for (int icg = 0; icg < 4; icg++) {
    const int icgG = ks * 4 + icg;
    const long icoff = (long)icgG * 8;
    // per-lane weight base (shorts): ((tap*32 + icgG)*256 + oc)*8
    const long wb0 = ((long)icgG * 256 + wv * 64 + ln16) * 8 + (long)q * 65536;

    // ---------------- HI phase: A_hi * (B_hi + B_lo) ----------------
    __syncthreads();
    for (int idx = t; idx < 1600; idx += 256) {
      int im = idx / 400, p = idx - im * 400;
      int iy = p / 20, ix = p - iy * 20;
      int dst = (ix & 1) * 6400 + im * 1600 + iy * 80 + (ix >> 1) * 8;
      *(uint4*)&slabA[dst] =
          *(const uint4*)&xhi[((long)(b0 + im) * 400 + p) * 256 + icoff];
    }
    __syncthreads();

    {
      bf16x8 cbh[4];
#pragma unroll
      for (int nt = 0; nt < 4; nt++) cbh[nt] = *(const bf16x8*)&whi[wb0 + nt * 128];
#pragma unroll 1
      for (int kst = 0; kst < 21; kst++) {
        const int t0n = (kst < 20) ? (kst + 1) * 4 : 80;
        // prefetch next k-step's B-hi; load this k-step's B-lo (used after
        // the 36-MFMA hi block -- L2 latency covered)
        bf16x8 nbh[4], cbl[4];
#pragma unroll
        for (int nt = 0; nt < 4; nt++) {
          nbh[nt] = *(const bf16x8*)&whi[wb0 + (long)t0n * 65536 + nt * 128];
          cbl[nt] = *(const bf16x8*)&wlo[wb0 + (long)(kst * 4) * 65536 + nt * 128];
        }
        const int tap = kst * 4 + q;
        const int i = tap / 9, j = tap - i * 9;
        const int aoff = (j & 1) * 6400 + i * 80 + (j >> 1) * 8;
        // 3 batches of 3 mt: 3 ds_reads then 12 hi + 12 lo independent MFMAs
#pragma unroll
        for (int bb = 0; bb < 3; bb++) {
          bf16x8 av[3];
#pragma unroll
          for (int m3 = 0; m3 < 3; m3++)
            av[m3] = *(const bf16x8*)&slabA[aoff + combo[bb * 3 + m3]];
#pragma unroll
          for (int nt = 0; nt < 4; nt++)
#pragma unroll
            for (int m3 = 0; m3 < 3; m3++)
              acc[bb * 3 + m3][nt] = __builtin_amdgcn_mfma_f32_16x16x32_bf16(
                  av[m3], cbh[nt], acc[bb * 3 + m3][nt], 0, 0, 0);
#pragma unroll
          for (int nt = 0; nt < 4; nt++)
#pragma unroll
            for (int m3 = 0; m3 < 3; m3++)
              acc[bb * 3 + m3][nt] = __builtin_amdgcn_mfma_f32_16x16x32_bf16(
                  av[m3], cbl[nt], acc[bb * 3 + m3][nt], 0, 0, 0);
        }
#pragma unroll
        for (int nt = 0; nt < 4; nt++) cbh[nt] = nbh[nt];
      }
    }

    // ---------------- LO phase: A_lo * B_hi ----------------
    __syncthreads();
    for (int idx = t; idx < 1600; idx += 256) {
      int im = idx / 400, p = idx - im * 400;
      int iy = p / 20, ix = p - iy * 20;
      int dst = (ix & 1) * 6400 + im * 1600 + iy * 80 + (ix >> 1) * 8;
      *(uint4*)&slabA[dst] =
          *(const uint4*)&xlo[((long)(b0 + im) * 400 + p) * 256 + icoff];
    }
    __syncthreads();

    {
      bf16x8 cbh[4];
#pragma unroll
      for (int nt = 0; nt < 4; nt++) cbh[nt] = *(const bf16x8*)&whi[wb0 + nt * 128];
#pragma unroll 1
      for (int kst = 0; kst < 21; kst++) {
        const int t0n = (kst < 20) ? (kst + 1) * 4 : 80;
        bf16x8 nbh[4];
#pragma unroll
        for (int nt = 0; nt < 4; nt++)
          nbh[nt] = *(const bf16x8*)&whi[wb0 + (long)t0n * 65536 + nt * 128];
        const int tap = kst * 4 + q;
        const int i = tap / 9, j = tap - i * 9;
        const int aoff = (j & 1) * 6400 + i * 80 + (j >> 1) * 8;
#pragma unroll
        for (int bb = 0; bb < 3; bb++) {
          bf16x8 av[3];
#pragma unroll
          for (int m3 = 0; m3 < 3; m3++)
            av[m3] = *(const bf16x8*)&slabA[aoff + combo[bb * 3 + m3]];
#pragma unroll
          for (int nt = 0; nt < 4; nt++)
#pragma unroll
            for (int m3 = 0; m3 < 3; m3++)
              acc[bb * 3 + m3][nt] = __builtin_amdgcn_mfma_f32_16x16x32_bf16(
                  av[m3], cbh[nt], acc[bb * 3 + m3][nt], 0, 0, 0);
        }
#pragma unroll
        for (int nt = 0; nt < 4; nt++) cbh[nt] = nbh[nt];
      }
    }
  }

  // epilogue: C/D layout col(n)=lane&15, row(m)=q*4+r; atomic over 8 ic-splits
#pragma unroll
  for (int mt = 0; mt < 9; mt++)
#pragma unroll
    for (int nt = 0; nt < 4; nt++) {
      int oc = wv * 64 + nt * 16 + ln16;
      int rowb = mb * 144 + mt * 16 + q * 4;
#pragma unroll
      for (int r = 0; r < 4; r++)
        atomicAdd(&y2[(long)(rowb + r) * 256 + oc], acc[mt][nt][r]);
    }
}

// ================= primary caps squash + predictions + routing ==============
// grid 8192 = g*256 + b; block 256.  y2 layout: [b][pos(36)][c(256)], pre-bias.
__global__ __launch_bounds__(256) void caps_k(
    const float* __restrict__ y2, const float* __restrict__ b2,
    const float* __restrict__ Wcaps, const float* __restrict__ b_route,
    float* __restrict__ vpart) {
  __shared__ float u[288];
  __shared__ float usc[36];
  __shared__ float up[5760];
  __shared__ float bl[360];
  __shared__ float cl[360];
  __shared__ float sv[160];
  __shared__ float vv[160];
  __shared__ float scale[10];
  const int blk = blockIdx.x;
  const int g = blk >> 8, b = blk & 255;
  const int t = threadIdx.x;

  for (int idx = t; idx < 288; idx += 256) {
    int s = idx >> 3, d = idx & 7;
    u[idx] = y2[((long)b * 36 + s) * 256 + g * 8 + d] + b2[g * 8 + d];
  }
  for (int idx = t; idx < 360; idx += 256) bl[idx] = b_route[g * 360 + idx];
  __syncthreads();
  if (t < 36) {
    float l2 = 0.f;
#pragma unroll
    for (int d = 0; d < 8; d++) { float v = u[t * 8 + d]; l2 = fmaf(v, v, l2); }
    float l = sqrtf(l2);
    usc[t] = (l2 / (1.f + l2)) / (l + 1e-8f);
  }
  __syncthreads();
  for (int idx = t; idx < 288; idx += 256) u[idx] *= usc[idx >> 3];
  __syncthreads();
  for (int idx = t; idx < 5760; idx += 256) {
    int s = idx / 160, k = idx - s * 160;
    const float* wp = Wcaps + (g * 36 + s) * 8 * 160 + k;
    float a = 0.f;
#pragma unroll
    for (int d = 0; d < 8; d++) a = fmaf(u[s * 8 + d], wp[d * 160], a);
    up[idx] = a;
  }
  __syncthreads();

  for (int r = 0; r < 3; r++) {
    if (t < 36) {
      float m = bl[t * 10];
#pragma unroll
      for (int oc = 1; oc < 10; oc++) m = fmaxf(m, bl[t * 10 + oc]);
      float e[10]; float sum = 0.f;
#pragma unroll
      for (int oc = 0; oc < 10; oc++) { e[oc] = expf(bl[t * 10 + oc] - m); sum += e[oc]; }
      float inv = 1.f / sum;
#pragma unroll
      for (int oc = 0; oc < 10; oc++) cl[t * 10 + oc] = e[oc] * inv;
    }
    __syncthreads();
    if (t < 160) {
      const int oc = t >> 4;
      float a = 0.f;
#pragma unroll 1
      for (int s = 0; s < 36; s++) a = fmaf(cl[s * 10 + oc], up[s * 160 + t], a);
      sv[t] = a;
    }
    __syncthreads();
    if (t < 10) {
      float l2 = 0.f;
#pragma unroll
      for (int od = 0; od < 16; od++) { float v = sv[t * 16 + od]; l2 = fmaf(v, v, l2); }
      scale[t] = (l2 / (1.f + l2)) / (sqrtf(l2) + 1e-8f);
    }
    __syncthreads();
    if (t < 160) vv[t] = sv[t] * scale[t >> 4];
    __syncthreads();
    if (r < 2) {
      for (int idx = t; idx < 360; idx += 256) {
        int s = idx / 10, oc = idx - s * 10;
        float a = 0.f;
#pragma unroll
        for (int od = 0; od < 16; od++)
          a = fmaf(up[s * 160 + oc * 16 + od], vv[oc * 16 + od], a);
        bl[idx] += a;
      }
      __syncthreads();
    }
  }
  if (t < 160) vpart[(b * 32 + g) * 160 + t] = vv[t];
}

// ================== final: sum over groups + probs ==========================
__global__ __launch_bounds__(192) void final_k(
    const float* __restrict__ vpart, float* __restrict__ out) {
  __shared__ float v[160];
  const int b = blockIdx.x, t = threadIdx.x;
  if (t < 160) {
    float a = 0.f;
#pragma unroll 1
    for (int g = 0; g < 32; g++) a += vpart[(b * 32 + g) * 160 + t];
    v[t] = a;
    out[b * 160 + t] = a;
  }
  __syncthreads();
  if (t < 10) {
    float l2 = 0.f;
#pragma unroll
    for (int od = 0; od < 16; od++) { float x = v[t * 16 + od]; l2 = fmaf(x, x, l2); }
    out[40960 + b * 10 + t] = sqrtf(l2);
  }
}

// ===========================================================================
extern "C" void kernel_launch(void* const* d_in, const int* in_sizes, int n_in,
                              void* d_out, int out_size, void* d_ws, size_t ws_size,
                              hipStream_t stream) {
  const float* inp     = (const float*)d_in[0];
  const float* W1      = (const float*)d_in[1];
  const float* b1      = (const float*)d_in[2];
  const float* W2      = (const float*)d_in[3];
  const float* b2      = (const float*)d_in[4];
  const float* Wcaps   = (const float*)d_in[5];
  const float* b_route = (const float*)d_in[6];
  float* out = (float*)d_out;
  char* ws = (char*)d_ws;

  short* xhi = (short*)(ws + XHI_OFF);
  short* xlo = (short*)(ws + XLO_OFF);
  short* whi = (short*)(ws + WHI_OFF);
  short* wlo = (short*)(ws + WLO_OFF);
  float* y2  = (float*)(ws + Y2_OFF);
  float* vp  = (float*)(ws + VP_OFF);

  hipMemsetAsync(y2, 0, Y2_BYTES, stream);
  conv1_k <<<2048, 320, 0, stream>>>(inp, W1, b1, xhi, xlo);
  wtrans_k<<<21504, 256, 0, stream>>>(W2, whi, wlo);
  conv2_k <<<512, 256, 0, stream>>>(xhi, xlo, whi, wlo, y2);
  caps_k  <<<8192, 256, 0, stream>>>(y2, b2, Wcaps, b_route, vp);
  final_k <<<256, 192, 0, stream>>>(vp, out);
}